// Round 1
// baseline (7557.872 us; speedup 1.0000x reference)
//
#include <hip/hip_runtime.h>

#define T_STEPS 1024
#define BATCH   256
#define DIM     128
#define HID     256
#define NSLICE  8                  // blocks per batch-group (N-split)
#define BT      16                 // batch tile per group
#define NGROUP  (BATCH / BT)       // 16
#define NBLOCK  (NGROUP * NSLICE)  // 128
#define JW      (HID / NSLICE)     // 32 h-indices per block

// LDS layout (bytes)
#define U_OFF    0        // [128][256] bf16, swizzled   (U rows q*H+jb+jj)
#define W_OFF    65536    // [128][128] bf16, swizzled
#define WD_OFF   98304    // [32][256]  bf16, swizzled
#define H_OFF    114688   // [16][256]  bf16, swizzled (h tile)
#define C_OFF    122880   // [16][256]  bf16, swizzled (c tile)
#define GST_OFF  131072   // [16][128] f32 gates staging
#define CST_OFF  139264   // [16][32]  f32 Cs staging
#define COWN_OFF 141312   // [16][32]  f32 local c (full precision)
#define BV_OFF   143360   // [128] f32 bias slice
#define BD_OFF   143872   // [32]  f32 bd slice
#define SMEM_TOTAL 144000

typedef float f32x4 __attribute__((ext_vector_type(4)));
typedef short bf16x8 __attribute__((ext_vector_type(8)));

__device__ __forceinline__ unsigned short f2bf(float f) {
    union { float f; unsigned u; } v; v.f = f;
    unsigned r = (v.u + 0x7fffu + ((v.u >> 16) & 1u)) >> 16;   // RNE
    return (unsigned short)r;
}
__device__ __forceinline__ float sigm(float v) { return 1.0f / (1.0f + __expf(-v)); }
__device__ __forceinline__ float tanh_fast(float v) {
    const float e = __expf(2.0f * v);
    return 1.0f - 2.0f / (e + 1.0f);   // correct limits at +/-inf
}

__global__ __launch_bounds__(512)
void tlstm_kernel(const float* __restrict__ x,
                  const float* __restrict__ dts,
                  const float* __restrict__ h0,
                  const float* __restrict__ c0,
                  const float* __restrict__ W,
                  const float* __restrict__ U,
                  const float* __restrict__ bvec,
                  const float* __restrict__ Wd,
                  const float* __restrict__ bd,
                  float* __restrict__ out,
                  unsigned int* ctr,
                  unsigned long long* hbuf,
                  unsigned long long* cbuf)
{
    extern __shared__ char smem[];
    float* gates_st = (float*)(smem + GST_OFF);
    float* cs_st    = (float*)(smem + CST_OFF);
    float* c_own    = (float*)(smem + COWN_OFF);
    float* bvals    = (float*)(smem + BV_OFF);
    float* bdvals   = (float*)(smem + BD_OFF);

    const int tid = threadIdx.x;
    const int g  = blockIdx.x / NSLICE;   // batch group
    const int s  = blockIdx.x % NSLICE;   // h-slice
    const int bb = g * BT;
    const int jb = s * JW;

    // ---- one-time: weights -> LDS (bf16, XOR-swizzled rows: byte ^= (row&7)<<4) ----
    for (int idx = tid; idx < 128 * 256; idx += 512) {
        const int r = idx >> 8, k = idx & 255;
        const int urow = ((r >> 5) * HID) + jb + (r & 31);   // q*H + jb + jj
        int bo = (r << 9) + (k << 1); bo ^= (r & 7) << 4;
        *(unsigned short*)(smem + U_OFF + bo) = f2bf(U[(size_t)urow * HID + k]);
    }
    for (int idx = tid; idx < 128 * 128; idx += 512) {
        const int r = idx >> 7, k = idx & 127;
        const int wrow = ((r >> 5) * HID) + jb + (r & 31);
        int bo = (r << 8) + (k << 1); bo ^= (r & 7) << 4;
        *(unsigned short*)(smem + W_OFF + bo) = f2bf(W[(size_t)wrow * DIM + k]);
    }
    for (int idx = tid; idx < 32 * 256; idx += 512) {
        const int r = idx >> 8, k = idx & 255;
        int bo = (r << 9) + (k << 1); bo ^= (r & 7) << 4;
        *(unsigned short*)(smem + WD_OFF + bo) = f2bf(Wd[(size_t)(jb + r) * HID + k]);
    }
    if (tid < 128) bvals[tid] = bvec[((tid >> 5) * HID) + jb + (tid & 31)];
    if (tid < 32)  bdvals[tid] = bd[jb + tid];

    // ---- init: local c (f32) + publish h0/c0 (bf16, agent scope) ----
    const int b_ = tid >> 5;   // 0..15 batch within tile
    const int jj = tid & 31;   // 0..31 h-index within slice
    {
        const float h0v = h0[(size_t)(bb + b_) * HID + jb + jj];
        const float c0v = c0[(size_t)(bb + b_) * HID + jb + jj];
        c_own[tid] = c0v;
        const unsigned short hb16 = f2bf(h0v), cb16 = f2bf(c0v);
        const int oh = __shfl_xor((int)hb16, 1);
        const int oc = __shfl_xor((int)cb16, 1);
        if ((jj & 1) == 0) {
            const unsigned int hw = (unsigned)hb16 | ((unsigned)oh << 16);
            const unsigned int cw = (unsigned)cb16 | ((unsigned)oc << 16);
            const size_t ei = ((size_t)(bb + b_) * HID + jb + jj) >> 1;
            __hip_atomic_store((unsigned int*)hbuf + ei, hw, __ATOMIC_RELAXED, __HIP_MEMORY_SCOPE_AGENT);
            __hip_atomic_store((unsigned int*)cbuf + ei, cw, __ATOMIC_RELAXED, __HIP_MEMORY_SCOPE_AGENT);
        }
    }
    __syncthreads();  // drains vmem per-wave before barrier
    if (tid == 0)
        __hip_atomic_fetch_add(&ctr[g << 5], 1u, __ATOMIC_RELEASE, __HIP_MEMORY_SCOPE_AGENT);
    if (tid < 64) {
        while (__hip_atomic_load(&ctr[g << 5], __ATOMIC_ACQUIRE, __HIP_MEMORY_SCOPE_AGENT)
               < (unsigned)NSLICE) {}
    }
    __syncthreads();

    const int lane = tid & 63;
    const int wid  = tid >> 6;     // 0..7
    const int lrow = lane & 15;    // A-row(batch) / B-col(weight row) / D-col
    const int lkg  = lane >> 4;    // K-group 0..3
    const int n0   = wid << 4;     // gates column base for this wave

    for (int t = 0; t < T_STEPS; ++t) {
        const int cur = t & 1;
        const unsigned long long* hsrc = hbuf + (size_t)cur * (BATCH * HID / 4);
        const unsigned long long* csrc = cbuf + (size_t)cur * (BATCH * HID / 4);

        // ---- stage h,c tiles (16x256 bf16 each) into LDS, swizzled ----
        #pragma unroll
        for (int rep = 0; rep < 2; ++rep) {
            const int idx = tid + rep * 512;       // 0..1023
            const int row = idx >> 6, qk = idx & 63;
            const unsigned long long hq = __hip_atomic_load(
                (unsigned long long*)(hsrc + (size_t)(bb + row) * (HID / 4) + qk),
                __ATOMIC_RELAXED, __HIP_MEMORY_SCOPE_AGENT);
            const unsigned long long cq = __hip_atomic_load(
                (unsigned long long*)(csrc + (size_t)(bb + row) * (HID / 4) + qk),
                __ATOMIC_RELAXED, __HIP_MEMORY_SCOPE_AGENT);
            int bo = (row << 9) + (qk << 3); bo ^= (row & 7) << 4;
            *(unsigned long long*)(smem + H_OFF + bo) = hq;
            *(unsigned long long*)(smem + C_OFF + bo) = cq;
        }

        // ---- x A-fragments straight from global (f32 -> bf16) ----
        bf16x8 xa[4];
        {
            const float* xp = x + ((size_t)t * BATCH + bb + lrow) * DIM + (lkg << 3);
            #pragma unroll
            for (int kc = 0; kc < 4; ++kc) {
                const float4 f0 = *(const float4*)(xp + kc * 32);
                const float4 f1 = *(const float4*)(xp + kc * 32 + 4);
                bf16x8 a;
                a[0] = (short)f2bf(f0.x); a[1] = (short)f2bf(f0.y);
                a[2] = (short)f2bf(f0.z); a[3] = (short)f2bf(f0.w);
                a[4] = (short)f2bf(f1.x); a[5] = (short)f2bf(f1.y);
                a[6] = (short)f2bf(f1.z); a[7] = (short)f2bf(f1.w);
                xa[kc] = a;
            }
        }
        __syncthreads();   // h/c staged

        // ---- gates tile: cols [n0,n0+16) ----
        f32x4 accX = {0.f, 0.f, 0.f, 0.f};
        f32x4 accH = {0.f, 0.f, 0.f, 0.f};
        {
            const int wr = n0 + lrow;
            #pragma unroll
            for (int kc = 0; kc < 4; ++kc) {       // x @ W^T, K=128
                int wo = (wr << 8) + ((kc * 32 + (lkg << 3)) << 1); wo ^= (wr & 7) << 4;
                const bf16x8 wv = *(const bf16x8*)(smem + W_OFF + wo);
                accX = __builtin_amdgcn_mfma_f32_16x16x32_bf16(xa[kc], wv, accX, 0, 0, 0);
            }
            #pragma unroll
            for (int kc = 0; kc < 8; ++kc) {       // h @ U^T, K=256
                int ao = (lrow << 9) + ((kc * 32 + (lkg << 3)) << 1); ao ^= (lrow & 7) << 4;
                const bf16x8 av = *(const bf16x8*)(smem + H_OFF + ao);
                int uo = (wr << 9) + ((kc * 32 + (lkg << 3)) << 1); uo ^= (wr & 7) << 4;
                const bf16x8 uv = *(const bf16x8*)(smem + U_OFF + uo);
                accH = __builtin_amdgcn_mfma_f32_16x16x32_bf16(av, uv, accH, 0, 0, 0);
            }
        }
        // ---- Cs pre-activation: waves 0,1 ----
        if (wid < 2) {
            f32x4 accC = {0.f, 0.f, 0.f, 0.f};
            const int wr = (wid << 4) + lrow;
            #pragma unroll
            for (int kc = 0; kc < 8; ++kc) {       // c @ Wd^T, K=256
                int ao = (lrow << 9) + ((kc * 32 + (lkg << 3)) << 1); ao ^= (lrow & 7) << 4;
                const bf16x8 av = *(const bf16x8*)(smem + C_OFF + ao);
                int wo = (wr << 9) + ((kc * 32 + (lkg << 3)) << 1); wo ^= (wr & 7) << 4;
                const bf16x8 wv = *(const bf16x8*)(smem + WD_OFF + wo);
                accC = __builtin_amdgcn_mfma_f32_16x16x32_bf16(av, wv, accC, 0, 0, 0);
            }
            #pragma unroll
            for (int i = 0; i < 4; ++i)
                cs_st[((lkg << 2) + i) * 32 + (wid << 4) + lrow] = accC[i];
        }
        #pragma unroll
        for (int i = 0; i < 4; ++i)   // D: row=(lane>>4)*4+i (batch), col=lane&15
            gates_st[((lkg << 2) + i) * 128 + n0 + lrow] = accX[i] + accH[i];

        __syncthreads();

        // ---- elementwise T-LSTM update: one thread per (batch, h) ----
        {
            const float ipre = gates_st[b_ * 128 + jj]      + bvals[jj];
            const float fpre = gates_st[b_ * 128 + 32 + jj] + bvals[32 + jj];
            const float gpre = gates_st[b_ * 128 + 64 + jj] + bvals[64 + jj];
            const float opre = gates_st[b_ * 128 + 96 + jj] + bvals[96 + jj];
            const float cspre = cs_st[b_ * 32 + jj] + bdvals[jj];
            const float dtv  = dts[(size_t)(bb + b_) * T_STEPS + t];
            const float gdt  = 1.0f / __logf(2.718281828459045f + dtv);
            const float Cs    = tanh_fast(cspre);
            const float cp    = c_own[tid];
            const float cstar = cp - Cs + Cs * gdt;
            const float cn    = sigm(fpre) * cstar + sigm(ipre) * tanh_fast(gpre);
            const float hn    = sigm(opre) * tanh_fast(cn);
            c_own[tid] = cn;
            out[((size_t)t * BATCH + bb + b_) * HID + jb + jj] = hn;

            const unsigned short hb16 = f2bf(hn), cb16 = f2bf(cn);
            const int oh = __shfl_xor((int)hb16, 1);
            const int oc = __shfl_xor((int)cb16, 1);
            if ((jj & 1) == 0) {
                const unsigned int hw = (unsigned)hb16 | ((unsigned)oh << 16);
                const unsigned int cw = (unsigned)cb16 | ((unsigned)oc << 16);
                const size_t ei = (size_t)(cur ^ 1) * (BATCH * HID / 2)
                                + (((size_t)(bb + b_) * HID + jb + jj) >> 1);
                __hip_atomic_store((unsigned int*)hbuf + ei, hw, __ATOMIC_RELAXED, __HIP_MEMORY_SCOPE_AGENT);
                __hip_atomic_store((unsigned int*)cbuf + ei, cw, __ATOMIC_RELAXED, __HIP_MEMORY_SCOPE_AGENT);
            }
            if (t == T_STEPS - 1) {
                const size_t base = (size_t)T_STEPS * BATCH * HID;
                out[base + (size_t)(bb + b_) * HID + jb + jj] = hn;
                out[base + (size_t)BATCH * HID + (size_t)(bb + b_) * HID + jb + jj] = cn;
            }
        }
        __syncthreads();   // drain publishes (waitcnt vmcnt(0) before s_barrier)

        // ---- 8-way group barrier (monotone counter, device scope) ----
        if (t < T_STEPS - 1) {
            if (tid == 0)
                __hip_atomic_fetch_add(&ctr[g << 5], 1u, __ATOMIC_RELEASE, __HIP_MEMORY_SCOPE_AGENT);
            if (tid < 64) {
                const unsigned target = (unsigned)(NSLICE * (t + 2));
                while (__hip_atomic_load(&ctr[g << 5], __ATOMIC_ACQUIRE, __HIP_MEMORY_SCOPE_AGENT)
                       < target) {}
            }
            __syncthreads();
        }
    }
}

extern "C" void kernel_launch(void* const* d_in, const int* in_sizes, int n_in,
                              void* d_out, int out_size, void* d_ws, size_t ws_size,
                              hipStream_t stream) {
    (void)in_sizes; (void)n_in; (void)out_size; (void)ws_size;
    const float* x   = (const float*)d_in[0];
    const float* dts = (const float*)d_in[1];
    const float* h0  = (const float*)d_in[2];
    const float* c0  = (const float*)d_in[3];
    const float* W   = (const float*)d_in[4];
    const float* U   = (const float*)d_in[5];
    const float* bv  = (const float*)d_in[6];
    const float* Wd  = (const float*)d_in[7];
    const float* bd  = (const float*)d_in[8];
    float* out = (float*)d_out;

    char* ws = (char*)d_ws;
    unsigned int*       ctr  = (unsigned int*)ws;                 // 16 groups * 128B
    unsigned long long* hbuf = (unsigned long long*)(ws + 4096);  // 2*256*256 bf16
    unsigned long long* cbuf = (unsigned long long*)(ws + 4096 + 262144);

    hipMemsetAsync(ctr, 0, NGROUP * 32 * sizeof(unsigned int), stream);
    hipFuncSetAttribute((const void*)tlstm_kernel,
                        hipFuncAttributeMaxDynamicSharedMemorySize, SMEM_TOTAL);
    tlstm_kernel<<<dim3(NBLOCK), dim3(512), SMEM_TOTAL, stream>>>(
        x, dts, h0, c0, W, U, bv, Wd, bd, out, ctr, hbuf, cbuf);
}

// Round 2
// 7295.393 us; speedup vs baseline: 1.0360x; 1.0360x over previous
//
#include <hip/hip_runtime.h>

#define T_STEPS 1024
#define BATCH   256
#define DIM     128
#define HID     256
#define NSLICE  8                  // blocks per batch-group (N-split)
#define BT      16                 // batch tile per group
#define NGROUP  (BATCH / BT)       // 16
#define NBLOCK  (NGROUP * NSLICE)  // 128
#define JW      (HID / NSLICE)     // 32 h-indices per block

// LDS layout (bytes)
#define U_OFF    0        // [128][256] bf16, swizzled   (U rows q*H+jb+jj)
#define W_OFF    65536    // [128][128] bf16, swizzled
#define WD_OFF   98304    // [32][256]  bf16, swizzled
#define H_OFF    114688   // [16][256]  bf16, swizzled (h tile)
#define C_OFF    122880   // [16][256]  bf16, swizzled (c tile)
#define GST_OFF  131072   // [16][132] f32 gates staging (padded stride)
#define CST_OFF  139520   // [16][33]  f32 Cs staging (padded stride)
#define SMEM_TOTAL 141632

typedef float f32x4 __attribute__((ext_vector_type(4)));
typedef short bf16x8 __attribute__((ext_vector_type(8)));

__device__ __forceinline__ unsigned short f2bf(float f) {
    union { float f; unsigned u; } v; v.f = f;
    unsigned r = (v.u + 0x7fffu + ((v.u >> 16) & 1u)) >> 16;   // RNE
    return (unsigned short)r;
}
__device__ __forceinline__ float sigm(float v) { return 1.0f / (1.0f + __expf(-v)); }
__device__ __forceinline__ float tanh_fast(float v) {
    const float e = __expf(2.0f * v);
    return 1.0f - 2.0f / (e + 1.0f);   // correct limits at +/-inf
}

__global__ __launch_bounds__(512)
void tlstm_kernel(const float* __restrict__ x,
                  const float* __restrict__ dts,
                  const float* __restrict__ h0,
                  const float* __restrict__ c0,
                  const float* __restrict__ W,
                  const float* __restrict__ U,
                  const float* __restrict__ bvec,
                  const float* __restrict__ Wd,
                  const float* __restrict__ bd,
                  float* __restrict__ out,
                  unsigned int* ctr,
                  unsigned long long* hbuf,
                  unsigned long long* cbuf)
{
    extern __shared__ char smem[];
    float* gates_st = (float*)(smem + GST_OFF);
    float* cs_st    = (float*)(smem + CST_OFF);

    const int tid = threadIdx.x;
    const int g  = blockIdx.x / NSLICE;   // batch group
    const int s  = blockIdx.x % NSLICE;   // h-slice
    const int bb = g * BT;
    const int jb = s * JW;

    const int lane = tid & 63;
    const int wid  = tid >> 6;     // 0..7
    const int lrow = lane & 15;    // A-row(batch) / B-col(weight row) / D-col
    const int lkg  = lane >> 4;    // K-group 0..3
    const int n0   = wid << 4;     // gates column base for this wave

    const int b_ = tid >> 5;   // 0..15 batch within tile (elementwise mapping)
    const int jj = tid & 31;   // 0..31 h-index within slice

    // ---- one-time: weights -> LDS (bf16, XOR-swizzled rows: byte ^= (row&7)<<4) ----
    for (int idx = tid; idx < 128 * 256; idx += 512) {
        const int r = idx >> 8, k = idx & 255;
        const int urow = ((r >> 5) * HID) + jb + (r & 31);   // q*H + jb + jj
        int bo = (r << 9) + (k << 1); bo ^= (r & 7) << 4;
        *(unsigned short*)(smem + U_OFF + bo) = f2bf(U[(size_t)urow * HID + k]);
    }
    for (int idx = tid; idx < 128 * 128; idx += 512) {
        const int r = idx >> 7, k = idx & 127;
        const int wrow = ((r >> 5) * HID) + jb + (r & 31);
        int bo = (r << 8) + (k << 1); bo ^= (r & 7) << 4;
        *(unsigned short*)(smem + W_OFF + bo) = f2bf(W[(size_t)wrow * DIM + k]);
    }
    for (int idx = tid; idx < 32 * 256; idx += 512) {
        const int r = idx >> 8, k = idx & 255;
        int bo = (r << 9) + (k << 1); bo ^= (r & 7) << 4;
        *(unsigned short*)(smem + WD_OFF + bo) = f2bf(Wd[(size_t)(jb + r) * HID + k]);
    }

    // ---- per-thread constants in registers ----
    const float bI = bvec[jb + jj];
    const float bF = bvec[HID + jb + jj];
    const float bG = bvec[2 * HID + jb + jj];
    const float bO = bvec[3 * HID + jb + jj];
    const float bD = bd[jb + jj];

    // ---- prefetch x(0) raw + dt(0) into registers ----
    float4 xr[8];
    float dt_cur;
    {
        const float* xp = x + ((size_t)0 * BATCH + bb + lrow) * DIM + (lkg << 3);
        #pragma unroll
        for (int kc = 0; kc < 4; ++kc) {
            xr[2 * kc]     = *(const float4*)(xp + kc * 32);
            xr[2 * kc + 1] = *(const float4*)(xp + kc * 32 + 4);
        }
        dt_cur = dts[(size_t)(bb + b_) * T_STEPS + 0];
    }

    // ---- init: local c (f32 register) + publish h0/c0 (bf16, agent scope) ----
    float c_reg;
    {
        const float h0v = h0[(size_t)(bb + b_) * HID + jb + jj];
        const float c0v = c0[(size_t)(bb + b_) * HID + jb + jj];
        c_reg = c0v;
        const unsigned short hb16 = f2bf(h0v), cb16 = f2bf(c0v);
        const int oh = __shfl_xor((int)hb16, 1);
        const int oc = __shfl_xor((int)cb16, 1);
        if ((jj & 1) == 0) {
            const unsigned int hw = (unsigned)hb16 | ((unsigned)oh << 16);
            const unsigned int cw = (unsigned)cb16 | ((unsigned)oc << 16);
            const size_t ei = ((size_t)(bb + b_) * HID + jb + jj) >> 1;
            __hip_atomic_store((unsigned int*)hbuf + ei, hw, __ATOMIC_RELAXED, __HIP_MEMORY_SCOPE_AGENT);
            __hip_atomic_store((unsigned int*)cbuf + ei, cw, __ATOMIC_RELAXED, __HIP_MEMORY_SCOPE_AGENT);
        }
    }
    __syncthreads();  // drains vmem per-wave before barrier
    if (tid == 0)
        __hip_atomic_fetch_add(&ctr[g << 5], 1u, __ATOMIC_RELEASE, __HIP_MEMORY_SCOPE_AGENT);
    if (tid == 0) {
        while (__hip_atomic_load(&ctr[g << 5], __ATOMIC_ACQUIRE, __HIP_MEMORY_SCOPE_AGENT)
               < (unsigned)NSLICE) {}
    }
    __syncthreads();

    float hn_keep = 0.0f;

    for (int t = 0; t < T_STEPS; ++t) {
        const int cur = t & 1;
        const unsigned long long* hsrc = hbuf + (size_t)cur * (BATCH * HID / 4);
        const unsigned long long* csrc = cbuf + (size_t)cur * (BATCH * HID / 4);

        // ---- stage h,c tiles (16x256 bf16 each) into LDS, swizzled ----
        #pragma unroll
        for (int rep = 0; rep < 2; ++rep) {
            const int idx = tid + rep * 512;       // 0..1023
            const int row = idx >> 6, qk = idx & 63;
            const unsigned long long hq = __hip_atomic_load(
                (unsigned long long*)(hsrc + (size_t)(bb + row) * (HID / 4) + qk),
                __ATOMIC_RELAXED, __HIP_MEMORY_SCOPE_AGENT);
            const unsigned long long cq = __hip_atomic_load(
                (unsigned long long*)(csrc + (size_t)(bb + row) * (HID / 4) + qk),
                __ATOMIC_RELAXED, __HIP_MEMORY_SCOPE_AGENT);
            int bo = (row << 9) + (qk << 3); bo ^= (row & 7) << 4;
            *(unsigned long long*)(smem + H_OFF + bo) = hq;
            *(unsigned long long*)(smem + C_OFF + bo) = cq;
        }

        // ---- deferred output store for step t-1 (off the barrier-drain path) ----
        if (t > 0)
            out[((size_t)(t - 1) * BATCH + bb + b_) * HID + jb + jj] = hn_keep;

        // ---- convert prefetched x -> bf16 A-fragments (pure VALU, overlaps staging) ----
        bf16x8 xa[4];
        #pragma unroll
        for (int kc = 0; kc < 4; ++kc) {
            const float4 f0 = xr[2 * kc];
            const float4 f1 = xr[2 * kc + 1];
            bf16x8 a;
            a[0] = (short)f2bf(f0.x); a[1] = (short)f2bf(f0.y);
            a[2] = (short)f2bf(f0.z); a[3] = (short)f2bf(f0.w);
            a[4] = (short)f2bf(f1.x); a[5] = (short)f2bf(f1.y);
            a[6] = (short)f2bf(f1.z); a[7] = (short)f2bf(f1.w);
            xa[kc] = a;
        }
        __syncthreads();   // #1: h/c staged

        // ---- gates tile: cols [n0,n0+16) ----
        f32x4 accX = {0.f, 0.f, 0.f, 0.f};
        f32x4 accH = {0.f, 0.f, 0.f, 0.f};
        {
            const int wr = n0 + lrow;
            #pragma unroll
            for (int kc = 0; kc < 4; ++kc) {       // x @ W^T, K=128
                int wo = (wr << 8) + ((kc * 32 + (lkg << 3)) << 1); wo ^= (wr & 7) << 4;
                const bf16x8 wv = *(const bf16x8*)(smem + W_OFF + wo);
                accX = __builtin_amdgcn_mfma_f32_16x16x32_bf16(xa[kc], wv, accX, 0, 0, 0);
            }
            #pragma unroll
            for (int kc = 0; kc < 8; ++kc) {       // h @ U^T, K=256
                int ao = (lrow << 9) + ((kc * 32 + (lkg << 3)) << 1); ao ^= (lrow & 7) << 4;
                const bf16x8 av = *(const bf16x8*)(smem + H_OFF + ao);
                int uo = (wr << 9) + ((kc * 32 + (lkg << 3)) << 1); uo ^= (wr & 7) << 4;
                const bf16x8 uv = *(const bf16x8*)(smem + U_OFF + uo);
                accH = __builtin_amdgcn_mfma_f32_16x16x32_bf16(av, uv, accH, 0, 0, 0);
            }
        }
        // ---- Cs pre-activation: waves 0,1 ----
        if (wid < 2) {
            f32x4 accC = {0.f, 0.f, 0.f, 0.f};
            const int wr = (wid << 4) + lrow;
            #pragma unroll
            for (int kc = 0; kc < 8; ++kc) {       // c @ Wd^T, K=256
                int ao = (lrow << 9) + ((kc * 32 + (lkg << 3)) << 1); ao ^= (lrow & 7) << 4;
                const bf16x8 av = *(const bf16x8*)(smem + C_OFF + ao);
                int wo = (wr << 9) + ((kc * 32 + (lkg << 3)) << 1); wo ^= (wr & 7) << 4;
                const bf16x8 wv = *(const bf16x8*)(smem + WD_OFF + wo);
                accC = __builtin_amdgcn_mfma_f32_16x16x32_bf16(av, wv, accC, 0, 0, 0);
            }
            #pragma unroll
            for (int i = 0; i < 4; ++i)
                cs_st[((lkg << 2) + i) * 33 + (wid << 4) + lrow] = accC[i];
        }
        #pragma unroll
        for (int i = 0; i < 4; ++i)   // D: row=(lane>>4)*4+i (batch), col=lane&15
            gates_st[((lkg << 2) + i) * 132 + n0 + lrow] = accX[i] + accH[i];

        __syncthreads();   // #2: gates staged

        // ---- elementwise T-LSTM update: one thread per (batch, h) ----
        float cn, hn;
        {
            const float ipre = gates_st[b_ * 132 + jj]      + bI;
            const float fpre = gates_st[b_ * 132 + 32 + jj] + bF;
            const float gpre = gates_st[b_ * 132 + 64 + jj] + bG;
            const float opre = gates_st[b_ * 132 + 96 + jj] + bO;
            const float cspre = cs_st[b_ * 33 + jj] + bD;
            const float gdt  = 1.0f / __logf(2.718281828459045f + dt_cur);
            const float Cs    = tanh_fast(cspre);
            const float cstar = c_reg - Cs + Cs * gdt;
            cn = sigm(fpre) * cstar + sigm(ipre) * tanh_fast(gpre);
            hn = sigm(opre) * tanh_fast(cn);
            c_reg = cn;
            hn_keep = hn;
        }

        if (t == T_STEPS - 1) {
            // final step: no publish/barrier needed; write out + tails directly
            out[((size_t)t * BATCH + bb + b_) * HID + jb + jj] = hn;
            const size_t base = (size_t)T_STEPS * BATCH * HID;
            out[base + (size_t)(bb + b_) * HID + jb + jj] = hn;
            out[base + (size_t)BATCH * HID + (size_t)(bb + b_) * HID + jb + jj] = cn;
            break;
        }

        // ---- publish h,c (bf16, agent scope) ----
        {
            const unsigned short hb16 = f2bf(hn), cb16 = f2bf(cn);
            const int oh = __shfl_xor((int)hb16, 1);
            const int oc = __shfl_xor((int)cb16, 1);
            if ((jj & 1) == 0) {
                const unsigned int hw = (unsigned)hb16 | ((unsigned)oh << 16);
                const unsigned int cw = (unsigned)cb16 | ((unsigned)oc << 16);
                const size_t ei = (size_t)(cur ^ 1) * (BATCH * HID / 2)
                                + (((size_t)(bb + b_) * HID + jb + jj) >> 1);
                __hip_atomic_store((unsigned int*)hbuf + ei, hw, __ATOMIC_RELAXED, __HIP_MEMORY_SCOPE_AGENT);
                __hip_atomic_store((unsigned int*)cbuf + ei, cw, __ATOMIC_RELAXED, __HIP_MEMORY_SCOPE_AGENT);
            }
        }
        __syncthreads();   // #3: drain publishes (vmcnt(0) before s_barrier)

        // ---- group barrier + hidden prefetch of x(t+1), dt(t+1) ----
        if (tid == 0)
            __hip_atomic_fetch_add(&ctr[g << 5], 1u, __ATOMIC_RELEASE, __HIP_MEMORY_SCOPE_AGENT);
        {
            const float* xp = x + ((size_t)(t + 1) * BATCH + bb + lrow) * DIM + (lkg << 3);
            #pragma unroll
            for (int kc = 0; kc < 4; ++kc) {
                xr[2 * kc]     = *(const float4*)(xp + kc * 32);
                xr[2 * kc + 1] = *(const float4*)(xp + kc * 32 + 4);
            }
            dt_cur = dts[(size_t)(bb + b_) * T_STEPS + (t + 1)];
        }
        if (tid == 0) {
            const unsigned target = (unsigned)(NSLICE * (t + 2));
            while (__hip_atomic_load(&ctr[g << 5], __ATOMIC_ACQUIRE, __HIP_MEMORY_SCOPE_AGENT)
                   < target) {}
        }
        __syncthreads();   // #4: release all waves into step t+1
    }
}

extern "C" void kernel_launch(void* const* d_in, const int* in_sizes, int n_in,
                              void* d_out, int out_size, void* d_ws, size_t ws_size,
                              hipStream_t stream) {
    (void)in_sizes; (void)n_in; (void)out_size; (void)ws_size;
    const float* x   = (const float*)d_in[0];
    const float* dts = (const float*)d_in[1];
    const float* h0  = (const float*)d_in[2];
    const float* c0  = (const float*)d_in[3];
    const float* W   = (const float*)d_in[4];
    const float* U   = (const float*)d_in[5];
    const float* bv  = (const float*)d_in[6];
    const float* Wd  = (const float*)d_in[7];
    const float* bd  = (const float*)d_in[8];
    float* out = (float*)d_out;

    char* ws = (char*)d_ws;
    unsigned int*       ctr  = (unsigned int*)ws;                 // 16 groups * 128B
    unsigned long long* hbuf = (unsigned long long*)(ws + 4096);  // 2*256*256 bf16
    unsigned long long* cbuf = (unsigned long long*)(ws + 4096 + 262144);

    hipMemsetAsync(ctr, 0, NGROUP * 32 * sizeof(unsigned int), stream);
    hipFuncSetAttribute((const void*)tlstm_kernel,
                        hipFuncAttributeMaxDynamicSharedMemorySize, SMEM_TOTAL);
    tlstm_kernel<<<dim3(NBLOCK), dim3(512), SMEM_TOTAL, stream>>>(
        x, dts, h0, c0, W, U, bv, Wd, bd, out, ctr, hbuf, cbuf);
}

// Round 3
// 4660.377 us; speedup vs baseline: 1.6217x; 1.5654x over previous
//
#include <hip/hip_runtime.h>

#define T_STEPS 1024
#define BATCH   256
#define DIM     128
#define HID     256
#define NSLICE  8                  // blocks per batch-group (N-split)
#define BT      16                 // batch tile per group
#define NGROUP  (BATCH / BT)       // 16
#define NBLOCK  (NGROUP * NSLICE)  // 128
#define JW      (HID / NSLICE)     // 32 h-indices per block

// LDS layout (bytes)
#define U_OFF    0        // [128][256] bf16, swizzled   (U rows q*H+jb+jj)
#define W_OFF    65536    // [128][128] bf16, swizzled
#define WD_OFF   98304    // [32][256]  bf16, swizzled
#define H_OFF    114688   // [16][256]  bf16, swizzled (h tile)
#define C_OFF    122880   // [16][256]  bf16, swizzled (c tile)
#define GST_OFF  131072   // [16][132] f32 gates staging (padded stride)
#define CST_OFF  139520   // [16][33]  f32 Cs staging (padded stride)
#define SMEM_TOTAL 141632

typedef float f32x4 __attribute__((ext_vector_type(4)));
typedef short bf16x8 __attribute__((ext_vector_type(8)));

__device__ __forceinline__ unsigned short f2bf(float f) {
    union { float f; unsigned u; } v; v.f = f;
    unsigned r = (v.u + 0x7fffu + ((v.u >> 16) & 1u)) >> 16;   // RNE
    return (unsigned short)r;
}
__device__ __forceinline__ float sigm(float v) { return 1.0f / (1.0f + __expf(-v)); }
__device__ __forceinline__ float tanh_fast(float v) {
    const float e = __expf(2.0f * v);
    return 1.0f - 2.0f / (e + 1.0f);   // correct limits at +/-inf
}

__global__ __launch_bounds__(512)
void tlstm_kernel(const float* __restrict__ x,
                  const float* __restrict__ dts,
                  const float* __restrict__ h0,
                  const float* __restrict__ c0,
                  const float* __restrict__ W,
                  const float* __restrict__ U,
                  const float* __restrict__ bvec,
                  const float* __restrict__ Wd,
                  const float* __restrict__ bd,
                  float* __restrict__ out,
                  unsigned int* ctr,
                  unsigned long long* hbuf,
                  unsigned long long* cbuf)
{
    extern __shared__ char smem[];
    float* gates_st = (float*)(smem + GST_OFF);
    float* cs_st    = (float*)(smem + CST_OFF);

    const int tid = threadIdx.x;
    const int g  = blockIdx.x / NSLICE;   // batch group
    const int s  = blockIdx.x % NSLICE;   // h-slice
    const int bb = g * BT;
    const int jb = s * JW;

    const int lane = tid & 63;
    const int wid  = tid >> 6;     // 0..7
    const int lrow = lane & 15;    // A-row(batch) / B-col(weight row) / D-col
    const int lkg  = lane >> 4;    // K-group 0..3
    const int n0   = wid << 4;     // gates column base for this wave

    const int b_ = tid >> 5;   // 0..15 batch within tile (elementwise mapping)
    const int jj = tid & 31;   // 0..31 h-index within slice

    // ---- one-time: weights -> LDS (bf16, XOR-swizzled rows: byte ^= (row&7)<<4) ----
    for (int idx = tid; idx < 128 * 256; idx += 512) {
        const int r = idx >> 8, k = idx & 255;
        const int urow = ((r >> 5) * HID) + jb + (r & 31);   // q*H + jb + jj
        int bo = (r << 9) + (k << 1); bo ^= (r & 7) << 4;
        *(unsigned short*)(smem + U_OFF + bo) = f2bf(U[(size_t)urow * HID + k]);
    }
    for (int idx = tid; idx < 128 * 128; idx += 512) {
        const int r = idx >> 7, k = idx & 127;
        const int wrow = ((r >> 5) * HID) + jb + (r & 31);
        int bo = (r << 8) + (k << 1); bo ^= (r & 7) << 4;
        *(unsigned short*)(smem + W_OFF + bo) = f2bf(W[(size_t)wrow * DIM + k]);
    }
    for (int idx = tid; idx < 32 * 256; idx += 512) {
        const int r = idx >> 8, k = idx & 255;
        int bo = (r << 9) + (k << 1); bo ^= (r & 7) << 4;
        *(unsigned short*)(smem + WD_OFF + bo) = f2bf(Wd[(size_t)(jb + r) * HID + k]);
    }

    // ---- per-thread constants in registers ----
    const float bI = bvec[jb + jj];
    const float bF = bvec[HID + jb + jj];
    const float bG = bvec[2 * HID + jb + jj];
    const float bO = bvec[3 * HID + jb + jj];
    const float bD = bd[jb + jj];

    // ---- prefetch x(0) raw + dt(0) into registers ----
    float4 xr[8];
    float dt_cur;
    {
        const float* xp = x + ((size_t)0 * BATCH + bb + lrow) * DIM + (lkg << 3);
        #pragma unroll
        for (int kc = 0; kc < 4; ++kc) {
            xr[2 * kc]     = *(const float4*)(xp + kc * 32);
            xr[2 * kc + 1] = *(const float4*)(xp + kc * 32 + 4);
        }
        dt_cur = dts[(size_t)(bb + b_) * T_STEPS + 0];
    }

    // ---- init: local c (f32 register) + publish h0/c0 (bf16, agent scope) ----
    float c_reg;
    {
        const float h0v = h0[(size_t)(bb + b_) * HID + jb + jj];
        const float c0v = c0[(size_t)(bb + b_) * HID + jb + jj];
        c_reg = c0v;
        const unsigned short hb16 = f2bf(h0v), cb16 = f2bf(c0v);
        const int oh = __shfl_xor((int)hb16, 1);
        const int oc = __shfl_xor((int)cb16, 1);
        if ((jj & 1) == 0) {
            const unsigned int hw = (unsigned)hb16 | ((unsigned)oh << 16);
            const unsigned int cw = (unsigned)cb16 | ((unsigned)oc << 16);
            const size_t ei = ((size_t)(bb + b_) * HID + jb + jj) >> 1;
            __hip_atomic_store((unsigned int*)hbuf + ei, hw, __ATOMIC_RELAXED, __HIP_MEMORY_SCOPE_AGENT);
            __hip_atomic_store((unsigned int*)cbuf + ei, cw, __ATOMIC_RELAXED, __HIP_MEMORY_SCOPE_AGENT);
        }
    }
    __syncthreads();  // drains vmem per-wave (vmcnt(0)) before the signal
    if (tid == 0)
        __hip_atomic_fetch_add(&ctr[g << 5], 1u, __ATOMIC_RELAXED, __HIP_MEMORY_SCOPE_AGENT);
    if (lane == 0) {   // each wave gates itself; no extra __syncthreads wake
        while (__hip_atomic_load(&ctr[g << 5], __ATOMIC_RELAXED, __HIP_MEMORY_SCOPE_AGENT)
               < (unsigned)NSLICE) {}
    }

    float hn_keep = 0.0f;

    for (int t = 0; t < T_STEPS; ++t) {
        const int cur = t & 1;
        const unsigned long long* hsrc = hbuf + (size_t)cur * (BATCH * HID / 4);
        const unsigned long long* csrc = cbuf + (size_t)cur * (BATCH * HID / 4);

        // ---- stage h,c tiles (16x256 bf16 each) into LDS, swizzled ----
        #pragma unroll
        for (int rep = 0; rep < 2; ++rep) {
            const int idx = tid + rep * 512;       // 0..1023
            const int row = idx >> 6, qk = idx & 63;
            const unsigned long long hq = __hip_atomic_load(
                (unsigned long long*)(hsrc + (size_t)(bb + row) * (HID / 4) + qk),
                __ATOMIC_RELAXED, __HIP_MEMORY_SCOPE_AGENT);
            const unsigned long long cq = __hip_atomic_load(
                (unsigned long long*)(csrc + (size_t)(bb + row) * (HID / 4) + qk),
                __ATOMIC_RELAXED, __HIP_MEMORY_SCOPE_AGENT);
            int bo = (row << 9) + (qk << 3); bo ^= (row & 7) << 4;
            *(unsigned long long*)(smem + H_OFF + bo) = hq;
            *(unsigned long long*)(smem + C_OFF + bo) = cq;
        }

        // ---- deferred output store for step t-1 (off the barrier-drain path) ----
        if (t > 0)
            out[((size_t)(t - 1) * BATCH + bb + b_) * HID + jb + jj] = hn_keep;

        // ---- convert prefetched x -> bf16 A-fragments (pure VALU, overlaps staging) ----
        bf16x8 xa[4];
        #pragma unroll
        for (int kc = 0; kc < 4; ++kc) {
            const float4 f0 = xr[2 * kc];
            const float4 f1 = xr[2 * kc + 1];
            bf16x8 a;
            a[0] = (short)f2bf(f0.x); a[1] = (short)f2bf(f0.y);
            a[2] = (short)f2bf(f0.z); a[3] = (short)f2bf(f0.w);
            a[4] = (short)f2bf(f1.x); a[5] = (short)f2bf(f1.y);
            a[6] = (short)f2bf(f1.z); a[7] = (short)f2bf(f1.w);
            xa[kc] = a;
        }
        __syncthreads();   // #1: h/c staged

        // ---- gates tile: cols [n0,n0+16) ----
        f32x4 accX = {0.f, 0.f, 0.f, 0.f};
        f32x4 accH = {0.f, 0.f, 0.f, 0.f};
        {
            const int wr = n0 + lrow;
            #pragma unroll
            for (int kc = 0; kc < 4; ++kc) {       // x @ W^T, K=128
                int wo = (wr << 8) + ((kc * 32 + (lkg << 3)) << 1); wo ^= (wr & 7) << 4;
                const bf16x8 wv = *(const bf16x8*)(smem + W_OFF + wo);
                accX = __builtin_amdgcn_mfma_f32_16x16x32_bf16(xa[kc], wv, accX, 0, 0, 0);
            }
            #pragma unroll
            for (int kc = 0; kc < 8; ++kc) {       // h @ U^T, K=256
                int ao = (lrow << 9) + ((kc * 32 + (lkg << 3)) << 1); ao ^= (lrow & 7) << 4;
                const bf16x8 av = *(const bf16x8*)(smem + H_OFF + ao);
                int uo = (wr << 9) + ((kc * 32 + (lkg << 3)) << 1); uo ^= (wr & 7) << 4;
                const bf16x8 uv = *(const bf16x8*)(smem + U_OFF + uo);
                accH = __builtin_amdgcn_mfma_f32_16x16x32_bf16(av, uv, accH, 0, 0, 0);
            }
        }
        // ---- Cs pre-activation: waves 0,1 ----
        if (wid < 2) {
            f32x4 accC = {0.f, 0.f, 0.f, 0.f};
            const int wr = (wid << 4) + lrow;
            #pragma unroll
            for (int kc = 0; kc < 8; ++kc) {       // c @ Wd^T, K=256
                int ao = (lrow << 9) + ((kc * 32 + (lkg << 3)) << 1); ao ^= (lrow & 7) << 4;
                const bf16x8 av = *(const bf16x8*)(smem + C_OFF + ao);
                int wo = (wr << 9) + ((kc * 32 + (lkg << 3)) << 1); wo ^= (wr & 7) << 4;
                const bf16x8 wv = *(const bf16x8*)(smem + WD_OFF + wo);
                accC = __builtin_amdgcn_mfma_f32_16x16x32_bf16(av, wv, accC, 0, 0, 0);
            }
            #pragma unroll
            for (int i = 0; i < 4; ++i)
                cs_st[((lkg << 2) + i) * 33 + (wid << 4) + lrow] = accC[i];
        }
        #pragma unroll
        for (int i = 0; i < 4; ++i)   // D: row=(lane>>4)*4+i (batch), col=lane&15
            gates_st[((lkg << 2) + i) * 132 + n0 + lrow] = accX[i] + accH[i];

        __syncthreads();   // #2: gates staged

        // ---- elementwise T-LSTM update: one thread per (batch, h) ----
        float cn, hn;
        {
            const float ipre = gates_st[b_ * 132 + jj]      + bI;
            const float fpre = gates_st[b_ * 132 + 32 + jj] + bF;
            const float gpre = gates_st[b_ * 132 + 64 + jj] + bG;
            const float opre = gates_st[b_ * 132 + 96 + jj] + bO;
            const float cspre = cs_st[b_ * 33 + jj] + bD;
            const float gdt  = 1.0f / __logf(2.718281828459045f + dt_cur);
            const float Cs    = tanh_fast(cspre);
            const float cstar = c_reg - Cs + Cs * gdt;
            cn = sigm(fpre) * cstar + sigm(ipre) * tanh_fast(gpre);
            hn = sigm(opre) * tanh_fast(cn);
            c_reg = cn;
            hn_keep = hn;
        }

        if (t == T_STEPS - 1) {
            // final step: no publish/barrier needed; write out + tails directly
            out[((size_t)t * BATCH + bb + b_) * HID + jb + jj] = hn;
            const size_t base = (size_t)T_STEPS * BATCH * HID;
            out[base + (size_t)(bb + b_) * HID + jb + jj] = hn;
            out[base + (size_t)BATCH * HID + (size_t)(bb + b_) * HID + jb + jj] = cn;
            break;
        }

        // ---- publish h,c (bf16, agent scope, relaxed sc1 stores) ----
        {
            const unsigned short hb16 = f2bf(hn), cb16 = f2bf(cn);
            const int oh = __shfl_xor((int)hb16, 1);
            const int oc = __shfl_xor((int)cb16, 1);
            if ((jj & 1) == 0) {
                const unsigned int hw = (unsigned)hb16 | ((unsigned)oh << 16);
                const unsigned int cw = (unsigned)cb16 | ((unsigned)oc << 16);
                const size_t ei = (size_t)(cur ^ 1) * (BATCH * HID / 2)
                                + (((size_t)(bb + b_) * HID + jb + jj) >> 1);
                __hip_atomic_store((unsigned int*)hbuf + ei, hw, __ATOMIC_RELAXED, __HIP_MEMORY_SCOPE_AGENT);
                __hip_atomic_store((unsigned int*)cbuf + ei, cw, __ATOMIC_RELAXED, __HIP_MEMORY_SCOPE_AGENT);
            }
        }
        __syncthreads();   // #3: every wave drains its publishes (vmcnt(0)) before signal

        // ---- group barrier: relaxed add + per-wave relaxed poll; prefetch hidden ----
        if (tid == 0)
            __hip_atomic_fetch_add(&ctr[g << 5], 1u, __ATOMIC_RELAXED, __HIP_MEMORY_SCOPE_AGENT);
        {
            const float* xp = x + ((size_t)(t + 1) * BATCH + bb + lrow) * DIM + (lkg << 3);
            #pragma unroll
            for (int kc = 0; kc < 4; ++kc) {
                xr[2 * kc]     = *(const float4*)(xp + kc * 32);
                xr[2 * kc + 1] = *(const float4*)(xp + kc * 32 + 4);
            }
            dt_cur = dts[(size_t)(bb + b_) * T_STEPS + (t + 1)];
        }
        {
            const unsigned target = (unsigned)(NSLICE * (t + 2));
            if (lane == 0) {   // per-wave gate; wave reconverges after loop
                while (__hip_atomic_load(&ctr[g << 5], __ATOMIC_RELAXED, __HIP_MEMORY_SCOPE_AGENT)
                       < target) {}
            }
        }
        // no block-wide release barrier: each wave proceeds; LDS staging is
        // ordered by barrier #1 of the next iteration.
    }
}

extern "C" void kernel_launch(void* const* d_in, const int* in_sizes, int n_in,
                              void* d_out, int out_size, void* d_ws, size_t ws_size,
                              hipStream_t stream) {
    (void)in_sizes; (void)n_in; (void)out_size; (void)ws_size;
    const float* x   = (const float*)d_in[0];
    const float* dts = (const float*)d_in[1];
    const float* h0  = (const float*)d_in[2];
    const float* c0  = (const float*)d_in[3];
    const float* W   = (const float*)d_in[4];
    const float* U   = (const float*)d_in[5];
    const float* bv  = (const float*)d_in[6];
    const float* Wd  = (const float*)d_in[7];
    const float* bd  = (const float*)d_in[8];
    float* out = (float*)d_out;

    char* ws = (char*)d_ws;
    unsigned int*       ctr  = (unsigned int*)ws;                 // 16 groups * 128B
    unsigned long long* hbuf = (unsigned long long*)(ws + 4096);  // 2*256*256 bf16
    unsigned long long* cbuf = (unsigned long long*)(ws + 4096 + 262144);

    hipMemsetAsync(ctr, 0, NGROUP * 32 * sizeof(unsigned int), stream);
    hipFuncSetAttribute((const void*)tlstm_kernel,
                        hipFuncAttributeMaxDynamicSharedMemorySize, SMEM_TOTAL);
    tlstm_kernel<<<dim3(NBLOCK), dim3(512), SMEM_TOTAL, stream>>>(
        x, dts, h0, c0, W, U, bv, Wd, bd, out, ctr, hbuf, cbuf);
}